// Round 8
// baseline (619.123 us; speedup 1.0000x reference)
//
#include <hip/hip_runtime.h>
#include <hip/hip_bf16.h>
#include <math.h>

typedef __bf16 bf16;
typedef __bf16 bf16x8 __attribute__((ext_vector_type(8)));
typedef __bf16 bf16x4 __attribute__((ext_vector_type(4)));
typedef float f32x4 __attribute__((ext_vector_type(4)));
typedef short s16x4 __attribute__((ext_vector_type(4)));

#define S_LEN 2048
#define NTOK 8192          // B*S
#define DIM 1024
#define NH 16
#define HEADD 64
#define DFF 4096
#define MODD 6144          // 6*D
#define QSCALE 0.18033688011112042f   // 0.125 * log2(e), folded into q

// gelu(x) = 0.5x(1+tanh(u)) = x * sigmoid(2u); sigmoid via hw exp2+rcp.
__device__ __forceinline__ float gelu_fast(float x) {
  float u = 0.7978845608028654f * (x + 0.044715f * x * x * x);
  float e = __builtin_amdgcn_exp2f(-2.8853900817779268f * u);  // exp(-2u)
  return x * __builtin_amdgcn_rcpf(1.0f + e);
}

// 16B async global->LDS. LDS dest is wave-uniform base + lane*16 (HW rule);
// caller passes the per-wave base, per-lane global src.
__device__ __forceinline__ void gl_lds16(const bf16* g, bf16* l) {
  __builtin_amdgcn_global_load_lds(
      (const __attribute__((address_space(1))) unsigned int*)g,
      (__attribute__((address_space(3))) unsigned int*)l, 16, 0, 0);
}

// ---------------- mod = c @ ada_W + ada_b ----------------
__global__ __launch_bounds__(256) void init_mod_kernel(
    const float* __restrict__ ada_b, float* __restrict__ mod) {
  int i = blockIdx.x * 256 + threadIdx.x;   // 0..24575
  mod[i] = ada_b[i % MODD];
}

__global__ __launch_bounds__(256) void ada_gemm_kernel(
    const float* __restrict__ cnd, const float* __restrict__ W,
    float* __restrict__ mod) {
  int n = blockIdx.x * 256 + threadIdx.x;   // 0..6143
  int k0 = blockIdx.y * 128;
  float a0 = 0.f, a1 = 0.f, a2 = 0.f, a3 = 0.f;
  for (int k = k0; k < k0 + 128; ++k) {
    float w = W[(size_t)k * MODD + n];
    a0 = fmaf(cnd[k], w, a0);
    a1 = fmaf(cnd[1024 + k], w, a1);
    a2 = fmaf(cnd[2048 + k], w, a2);
    a3 = fmaf(cnd[3072 + k], w, a3);
  }
  atomicAdd(&mod[n], a0);
  atomicAdd(&mod[MODD + n], a1);
  atomicAdd(&mod[2 * MODD + n], a2);
  atomicAdd(&mod[3 * MODD + n], a3);
}

// ---------------- W (K,N) fp32 -> Wt (N,K) bf16 ----------------
__global__ __launch_bounds__(256) void transpose_cast_kernel(
    const float* __restrict__ W, bf16* __restrict__ Wt, int K, int N) {
  __shared__ float tile[32][33];
  int n0 = blockIdx.x * 32, k0 = blockIdx.y * 32;
  int r = threadIdx.x >> 3;
  int c4 = (threadIdx.x & 7) * 4;
  float4 v = *(const float4*)&W[(size_t)(k0 + r) * N + n0 + c4];
  tile[r][c4 + 0] = v.x; tile[r][c4 + 1] = v.y;
  tile[r][c4 + 2] = v.z; tile[r][c4 + 3] = v.w;
  __syncthreads();
  bf16x4 o;
  o[0] = (bf16)tile[c4 + 0][r];
  o[1] = (bf16)tile[c4 + 1][r];
  o[2] = (bf16)tile[c4 + 2][r];
  o[3] = (bf16)tile[c4 + 3][r];
  *(bf16x4*)&Wt[(size_t)(n0 + r) * K + k0 + c4] = o;
}

// ---------------- V part of qkv -> VT[b][h][d][s] ----------------
__global__ __launch_bounds__(256) void vtrans_kernel(
    const bf16* __restrict__ qkv, bf16* __restrict__ VT) {
  __shared__ __align__(16) bf16 t[64][72];
  const int bh = blockIdx.y;
  const int b = bh >> 4, h = bh & 15;
  const int s0 = blockIdx.x * 64;
  const int tid = threadIdx.x;
  {
    const int r = tid >> 2;
    const int c = (tid & 3) * 16;
    const bf16* src =
        qkv + (size_t)(b * S_LEN + s0 + r) * 3072 + 2048 + h * 64 + c;
    *(bf16x8*)&t[r][c] = *(const bf16x8*)src;
    *(bf16x8*)&t[r][c + 8] = *(const bf16x8*)(src + 8);
  }
  __syncthreads();
  {
    const int d = tid & 63;
    const int sc = (tid >> 6) * 16;
    bf16x8 o0, o1;
#pragma unroll
    for (int j = 0; j < 8; ++j) o0[j] = t[sc + j][d];
#pragma unroll
    for (int j = 0; j < 8; ++j) o1[j] = t[sc + 8 + j][d];
    bf16* dst = VT + (size_t)(bh * 64 + d) * S_LEN + s0 + sc;
    *(bf16x8*)dst = o0;
    *(bf16x8*)(dst + 8) = o1;
  }
}

// ---------------- LayerNorm + adaLN modulate -> bf16 ----------------
__global__ __launch_bounds__(256) void ln_mod_kernel(
    const float* __restrict__ x, const float* __restrict__ w,
    const float* __restrict__ mod, int sh_off, int sc_off,
    bf16* __restrict__ out) {
  __shared__ float red[8];
  const int row = blockIdx.x;
  const int b = row >> 11;          // row / 2048
  const int tid = threadIdx.x;
  const float4 v = ((const float4*)(x + (size_t)row * DIM))[tid];
  float s1 = v.x + v.y + v.z + v.w;
  float s2 = v.x * v.x + v.y * v.y + v.z * v.z + v.w * v.w;
  for (int off = 32; off > 0; off >>= 1) {
    s1 += __shfl_down(s1, off, 64);
    s2 += __shfl_down(s2, off, 64);
  }
  const int wid = tid >> 6;
  if ((tid & 63) == 0) { red[wid] = s1; red[4 + wid] = s2; }
  __syncthreads();
  s1 = red[0] + red[1] + red[2] + red[3];
  s2 = red[4] + red[5] + red[6] + red[7];
  const float mu = s1 * (1.0f / DIM);
  const float inv = rsqrtf(s2 * (1.0f / DIM) - mu * mu + 1e-5f);
  const int c = tid * 4;
  const float* mb = mod + (size_t)b * MODD;
  float xs[4] = {v.x, v.y, v.z, v.w};
  bf16x4 o;
#pragma unroll
  for (int j = 0; j < 4; ++j)
    o[j] = (bf16)(((xs[j] - mu) * inv) * w[c + j] * (1.0f + mb[sc_off + c + j]) +
                  mb[sh_off + c + j]);
  *(bf16x4*)(out + (size_t)row * DIM + c) = o;
}

// ---------------- bf16 MFMA GEMM, C = A(M,K) @ Bt(N,K)^T, fused epilogues ----
// 128x128 2-phase structure (kept for qkv / Wout / W2 as controls this round).
// EPI 1: Cf = resid + g[b,n]*acc              (Wout proj -> d_out)
// EPI 3: Cf = resid + g[b,n]*(acc + bias)     (W2 -> d_out)
// EPI 4: qkv: q/k cols get fused RMSNorm+RoPE (q additionally scaled by
//        QSCALE so attn's softmax can use exp2 directly), v cols plain bf16
template <int EPI, int MT, int BN>
__global__ __launch_bounds__(256) void gemm_bt(
    const bf16* __restrict__ A, const bf16* __restrict__ Bt,
    bf16* __restrict__ Cb, float* __restrict__ Cf,
    const float* __restrict__ bias, const float* __restrict__ gmod,
    const float* __restrict__ resid, const float* __restrict__ cosb,
    const float* __restrict__ sinb, const float* __restrict__ qw,
    const float* __restrict__ kw, int M, int N, int K) {
  constexpr int IM = MT / 32;              // acc row-tiles per wave (4)
  constexpr int JN = BN / 32;              // acc col-tiles per wave (4)
  constexpr int AG = MT / 64;              // gload issues for A (2)
  constexpr int BG = BN / 64;              // gload issues for B (2)
  __shared__ __align__(16) bf16 As[3][MT * 32];   // 3 x 8 KB
  __shared__ __align__(16) bf16 Bs[3][BN * 32];
  const int tid = threadIdx.x;
  const int wid = tid >> 6;
  const int lane = tid & 63;
  const int l15 = lane & 15;
  const int quad = lane >> 4;

  // XCD-aware remap (gy assumed divisible by 8)
  const int gx = gridDim.x;
  const int flat = blockIdx.x + gx * blockIdx.y;
  const int xcd = flat & 7;
  const int idx = flat >> 3;
  const int ychunk = gridDim.y >> 3;
  const int bx = idx % gx;
  const int by = xcd * ychunk + idx / gx;
  const int m0 = by * MT;
  const int n0 = bx * BN;

  const int wm = (wid & 1) * (MT / 2);
  const int wn = (wid >> 1) * (BN / 2);

  const int srow = wid * 16 + (lane >> 2);
  const int scol = (lane & 3) * 8;
  const bf16* Ap = A + (size_t)(m0 + srow) * K + scol;
  const bf16* Bp = Bt + (size_t)(n0 + srow) * K + scol;

  auto stage = [&](int buf, int kt) {
#pragma unroll
    for (int g = 0; g < AG; ++g)
      gl_lds16(Ap + (size_t)g * 64 * K + kt, As[buf] + g * 2048 + wid * 512);
#pragma unroll
    for (int g = 0; g < BG; ++g)
      gl_lds16(Bp + (size_t)g * 64 * K + kt, Bs[buf] + g * 2048 + wid * 512);
  };

  // prologue: tiles 0 and 1 in flight
  stage(0, 0);
  stage(1, 32);

  f32x4 acc[IM][JN] = {};
  const int NT = K >> 5;
  int cur = 0, stg = 2;

  for (int t = 0; t < NT; ++t) {
    if (t + 2 < NT) {
      stage(stg, (t + 2) << 5);
      asm volatile("s_waitcnt vmcnt(8)" ::: "memory");   // tile t landed
    } else if (t + 1 < NT) {
      asm volatile("s_waitcnt vmcnt(4)" ::: "memory");
    } else {
      asm volatile("s_waitcnt vmcnt(0)" ::: "memory");
    }
    __builtin_amdgcn_s_barrier();   // all waves' tile-t DMA visible

    bf16x8 af[IM], bfr[JN];
#pragma unroll
    for (int i = 0; i < IM; ++i)
      af[i] = *(const bf16x8*)&As[cur][(wm + i * 16 + l15) * 32 + quad * 8];
#pragma unroll
    for (int j = 0; j < JN; ++j)
      bfr[j] = *(const bf16x8*)&Bs[cur][(wn + j * 16 + l15) * 32 + quad * 8];
    __builtin_amdgcn_s_setprio(1);
#pragma unroll
    for (int i = 0; i < IM; ++i)
#pragma unroll
      for (int j = 0; j < JN; ++j)
        acc[i][j] = __builtin_amdgcn_mfma_f32_16x16x32_bf16(af[i], bfr[j],
                                                            acc[i][j], 0, 0, 0);
    __builtin_amdgcn_s_setprio(0);
    __builtin_amdgcn_s_barrier();   // gates next step's overwrite of buf cur-1
    cur = (cur == 2) ? 0 : cur + 1;
    stg = (stg == 2) ? 0 : stg + 1;
  }

  if (EPI == 4 && n0 < 2048) {
    // q/k columns: fused RMSNorm (over the 64-dim head) + RoPE.
    const bool isq = (n0 + wn) < 1024;
    const float* nw = isq ? qw : kw;
    const float osc = isq ? QSCALE : 1.0f;   // fold softmax scale into q
    float wv[4];
#pragma unroll
    for (int j = 0; j < 4; ++j) wv[j] = nw[j * 16 + l15];
#pragma unroll
    for (int i = 0; i < IM; ++i) {
#pragma unroll
      for (int r = 0; r < 4; ++r) {
        const int m = m0 + wm + i * 16 + quad * 4 + r;
        const int s = m & (S_LEN - 1);
        float v[4];
        float ss = 0.f;
#pragma unroll
        for (int j = 0; j < 4; ++j) { v[j] = acc[i][j][r]; ss += v[j] * v[j]; }
        ss += __shfl_xor(ss, 1, 64);
        ss += __shfl_xor(ss, 2, 64);
        ss += __shfl_xor(ss, 4, 64);
        ss += __shfl_xor(ss, 8, 64);
        const float inv = rsqrtf(ss * (1.0f / HEADD) + 1e-6f);
        float xn[4];
#pragma unroll
        for (int j = 0; j < 4; ++j) xn[j] = v[j] * inv * wv[j];
#pragma unroll
        for (int j = 0; j < 4; ++j) {
          const int d = j * 16 + l15;
          const float rot = (j < 2) ? -xn[j + 2] : xn[j - 2];
          const float o =
              (xn[j] * cosb[s * HEADD + d] + rot * sinb[s * HEADD + d]) * osc;
          Cb[(size_t)m * N + n0 + wn + d] = (bf16)o;
        }
      }
    }
    return;
  }

#pragma unroll
  for (int i = 0; i < IM; ++i) {
#pragma unroll
    for (int r = 0; r < 4; ++r) {
      const int m = m0 + wm + i * 16 + quad * 4 + r;   // C row = quad*4+reg
#pragma unroll
      for (int j = 0; j < JN; ++j) {
        const int n = n0 + wn + j * 16 + l15;          // C col = lane&15
        float v = acc[i][j][r];
        if (EPI == 0 || EPI == 4) {
          Cb[(size_t)m * N + n] = (bf16)v;
        } else if (EPI == 1) {
          const int b = m >> 11;
          Cf[(size_t)m * N + n] =
              resid[(size_t)m * N + n] + gmod[(size_t)b * MODD + n] * v;
        } else if (EPI == 2) {
          v += bias[n];
          Cb[(size_t)m * N + n] = (bf16)gelu_fast(v);
        } else {
          v += bias[n];
          const int b = m >> 11;
          Cf[(size_t)m * N + n] =
              resid[(size_t)m * N + n] + gmod[(size_t)b * MODD + n] * v;
        }
      }
    }
  }
}

// ---------------- 8-phase 256^2 GEMM (T3+T4), W1 only this round ------------
// 512 thr, 8 waves (2M x 4N), per-wave 128x64 output, BK=64, LDS 2x64 KB dbuf.
// Per K-tile: 4 sub-phases (ih-half x kk-slice), each =
//   { issue 2 global_load_lds for tile t+1 | ds_read one quadrant's frags |
//     setprio(1) 16 MFMA setprio(0) | s_barrier }.
// ONE counted vmcnt(2) per tile (phase 1): the 2 just-issued next-tile loads
// stay in flight across the barrier -- never vmcnt(0) in the main loop
// (m233: the 2-phase drain is 72% of its critical path; m218: counted vs
// drain-0 = +38-73%). Buffer safety: tile t+1 is staged into buf^1 (last
// read at tile t-1, gated by t-1's trailing barrier).
// EPI 2 only: Cb = bf16(gelu(acc + bias)).
__global__ __launch_bounds__(512) void gemm8(
    const bf16* __restrict__ A, const bf16* __restrict__ Bt,
    bf16* __restrict__ Cb, const float* __restrict__ bias, int M, int N,
    int K) {
  __shared__ __align__(16) bf16 As[2][16384];   // 2 x 32 KB: [row<256][k<64]
  __shared__ __align__(16) bf16 Bs[2][16384];
  const int tid = threadIdx.x;
  const int wid = tid >> 6;                // 0..7
  const int lane = tid & 63;
  const int l15 = lane & 15;
  const int quad = lane >> 4;
  const int wr = wid & 1;                  // M half (128 rows)
  const int wc = wid >> 1;                 // N quarter (64 cols)

  // XCD-aware remap (gy divisible by 8; W1: gx=16, gy=32)
  const int gx = gridDim.x;
  const int flat = blockIdx.x + gx * blockIdx.y;
  const int xcd = flat & 7;
  const int idx = flat >> 3;
  const int ychunk = gridDim.y >> 3;
  const int bx = idx % gx;
  const int by = xcd * ychunk + idx / gx;
  const int m0 = by * 256;
  const int n0 = bx * 256;

  // staging geometry: issue q in 0..7 (q<4: A rows q*64..+63; q>=4: B).
  // thread covers row q*64 + (tid>>3), k (tid&7)*8; LDS elem = q*4096 + tid*8
  // (wave base q*4096 + wid*512, lane slice implicit).
  const int rrow = tid >> 3;
  const int rcol = (tid & 7) * 8;
  const bf16* Ap = A + (size_t)(m0 + rrow) * K + rcol;
  const bf16* Bp = Bt + (size_t)(n0 + rrow) * K + rcol;

  auto stage2 = [&](int buf, int kt, int q0) {
#pragma unroll
    for (int q = q0; q < q0 + 2; ++q) {
      if (q < 4)
        gl_lds16(Ap + (size_t)q * 64 * K + kt, As[buf] + q * 4096 + wid * 512);
      else
        gl_lds16(Bp + (size_t)(q - 4) * 64 * K + kt,
                 Bs[buf] + (q - 4) * 4096 + wid * 512);
    }
  };

  // prologue: stage tile 0 fully into buf 0
  stage2(0, 0, 0); stage2(0, 0, 2); stage2(0, 0, 4); stage2(0, 0, 6);

  f32x4 acc[8][4] = {};
  const int NT = K >> 6;
  int cur = 0;

  for (int t = 0; t < NT; ++t) {
    const int ktn = (t + 1) << 6;
    int qp = 0;
#pragma unroll
    for (int kk = 0; kk < 2; ++kk) {
      bf16x8 bfr[4];
#pragma unroll
      for (int ih = 0; ih < 2; ++ih) {
        // stage 2 loads of tile t+1 into the other buffer
        if (t + 1 < NT) stage2(cur ^ 1, ktn, qp * 2);
        if (qp == 0) {
          if (t + 1 < NT)
            asm volatile("s_waitcnt vmcnt(2)" ::: "memory");  // tile t landed
          else
            asm volatile("s_waitcnt vmcnt(0)" ::: "memory");
          __builtin_amdgcn_s_barrier();   // all waves' tile-t DMA visible
        }
        if (ih == 0) {   // B frags for this kk, reused across both ih phases
#pragma unroll
          for (int j = 0; j < 4; ++j)
            bfr[j] = *(const bf16x8*)&Bs[cur][(wc * 64 + j * 16 + l15) * 64 +
                                              kk * 32 + quad * 8];
        }
        bf16x8 af[4];
#pragma unroll
        for (int ii = 0; ii < 4; ++ii)
          af[ii] = *(const bf16x8*)&As[cur][(wr * 128 + (ih * 4 + ii) * 16 +
                                             l15) * 64 + kk * 32 + quad * 8];
        __builtin_amdgcn_s_setprio(1);
#pragma unroll
        for (int ii = 0; ii < 4; ++ii)
#pragma unroll
          for (int j = 0; j < 4; ++j)
            acc[ih * 4 + ii][j] = __builtin_amdgcn_mfma_f32_16x16x32_bf16(
                af[ii], bfr[j], acc[ih * 4 + ii][j], 0, 0, 0);
        __builtin_amdgcn_s_setprio(0);
        __builtin_amdgcn_s_barrier();
        ++qp;
      }
    }
    cur ^= 1;
  }

  // EPI 2: Cb = bf16(gelu(acc + bias))
#pragma unroll
  for (int i = 0; i < 8; ++i) {
#pragma unroll
    for (int r = 0; r < 4; ++r) {
      const int m = m0 + wr * 128 + i * 16 + quad * 4 + r;
#pragma unroll
      for (int j = 0; j < 4; ++j) {
        const int n = n0 + wc * 64 + j * 16 + l15;
        float v = acc[i][j][r] + bias[n];
        Cb[(size_t)m * N + n] = (bf16)gelu_fast(v);
      }
    }
  }
}

// ---------------- flash attention: single-pass, full-rate PV ----------------
// q is pre-scaled by QSCALE in the qkv epilogue, so the softmax numerator is
// exp2(sc) directly (no fmaf, no shift -- any fixed shift cancels in the
// final division). Single-pass over 32 KV tiles, QBLK=128 -> 1024 blocks =
// 4/CU. K rows stored in LDS permuted by sig(p) so each lane's S^T C-frags
// hold exactly keys quad*8+j: P packs into 16x16x32 A-frags in registers,
// PV runs at full rate. psum via ones-frag MFMA; division is lane-local.
// XCD remap: 16 q-blocks of one bh on one XCD.
__global__ __launch_bounds__(256) void attn_kernel(
    const bf16* __restrict__ qkv, const bf16* __restrict__ VT,
    bf16* __restrict__ attn) {
  __shared__ __align__(16) bf16 Ks[4096];   // [sig(key)][feat], chunk^=(row&7)
  __shared__ __align__(16) bf16 Vs[4096];   // [feat d][key], chunk^=(d&7)
  const int flat = blockIdx.x + 16 * blockIdx.y;
  const int xcd = flat & 7;
  const int idx = flat >> 3;             // 0..127
  const int bh = xcd * 8 + (idx >> 4);   // 0..63
  const int qblk = idx & 15;
  const int b = bh >> 4;
  const int h = bh & 15;
  const int q0 = qblk * 128;
  const int tid = threadIdx.x;
  const int wid = tid >> 6;
  const int lane = tid & 63;
  const int l15 = lane & 15;
  const int quad = lane >> 4;

  // Q fragments (B-operand: n=qrow=l15, k=feat quad*8+j)
  bf16x8 aq[2][2];
#pragma unroll
  for (int i = 0; i < 2; ++i) {
    const int qrow = q0 + wid * 32 + i * 16 + l15;
    const size_t qbase = (size_t)(b * S_LEN + qrow) * (3 * DIM) + h * HEADD;
    aq[i][0] = *(const bf16x8*)(qkv + qbase + quad * 8);
    aq[i][1] = *(const bf16x8*)(qkv + qbase + 32 + quad * 8);
  }

  // staging: lane stages global key/feat row `lane`; K lands at permuted row
  const int ksrow = (lane & 32) | ((lane & 4) << 2) | ((lane & 24) >> 1) | (lane & 3);
  const int ksw = ksrow & 7;
  const int vsw = lane & 7;
  const bf16* krow =
      qkv + (size_t)(b * S_LEN + lane) * 3072 + DIM + h * HEADD;
  const bf16* vrow = VT + (size_t)(bh * 64 + lane) * S_LEN;

  bf16x8 kreg[2], vreg[2];
#pragma unroll
  for (int rr = 0; rr < 2; ++rr) {
    const int ck = wid + 4 * rr;
    kreg[rr] = *(const bf16x8*)(krow + ck * 8);
    vreg[rr] = *(const bf16x8*)(vrow + ck * 8);
  }

  const bf16 one = (bf16)1.0f;
  const bf16x8 ones8 = {one, one, one, one, one, one, one, one};
  f32x4 oacc[2][4] = {};
  f32x4 psacc[2] = {};    // rowsum C-frag: lane holds qrow quad*4+r

  for (int t = 0; t < 32; ++t) {
    __syncthreads();   // previous tile's LDS reads done
#pragma unroll
    for (int rr = 0; rr < 2; ++rr) {
      const int ck = wid + 4 * rr;
      *(bf16x8*)&Ks[ksrow * 64 + ((ck ^ ksw) << 3)] = kreg[rr];
      *(bf16x8*)&Vs[lane * 64 + ((ck ^ vsw) << 3)] = vreg[rr];
    }
    __syncthreads();
    if (t < 31) {     // prefetch next tile while computing this one
      krow += 64 * 3072;
      vrow += 64;
#pragma unroll
      for (int rr = 0; rr < 2; ++rr) {
        const int ck = wid + 4 * rr;
        kreg[rr] = *(const bf16x8*)(krow + ck * 8);
        vreg[rr] = *(const bf16x8*)(vrow + ck * 8);
      }
    }

    // S^T = K·Q^T  (A = permuted K rows, B = Q^T): D[sig(key)][qrow]
    f32x4 sc[2][4] = {};
    __builtin_amdgcn_s_setprio(1);
#pragma unroll
    for (int hh = 0; hh < 2; ++hh) {
#pragma unroll
      for (int cc = 0; cc < 4; ++cc) {
        const int row = cc * 16 + l15;
        const bf16x8 kf =
            *(const bf16x8*)&Ks[row * 64 + (((quad + 4 * hh) ^ (l15 & 7)) << 3)];
#pragma unroll
        for (int i = 0; i < 2; ++i)
          sc[i][cc] = __builtin_amdgcn_mfma_f32_16x16x32_bf16(kf, aq[i][hh],
                                                              sc[i][cc], 0, 0, 0);
      }
    }
    __builtin_amdgcn_s_setprio(0);

    // softmax numerator: p = exp2(sc) (scale folded into q; shift cancels
    // in the division). Pack P into 16x16x32 A-frags.
    // sc slot (cc=2*c2+(j>>2), r=j&3) holds physical key c2*32+quad*8+j.
    bf16x8 pf[2][2];
#pragma unroll
    for (int i = 0; i < 2; ++i)
#pragma unroll
      for (int c2 = 0; c2 < 2; ++c2) {
        bf16x8 pb;
#pragma unroll
        for (int j = 0; j < 8; ++j) {
          const float p =
              __builtin_amdgcn_exp2f(sc[i][2 * c2 + (j >> 2)][j & 3]);
          pb[j] = (bf16)p;
        }
        pf[i][c2] = pb;
      }

    // psum row-sums via ones B-frag, then O += P·V at full 16x16x32 rate
    __builtin_amdgcn_s_setprio(1);
#pragma unroll
    for (int i = 0; i < 2; ++i)
#pragma unroll
      for (int c2 = 0; c2 < 2; ++c2)
        psacc[i] = __builtin_amdgcn_mfma_f32_16x16x32_bf16(pf[i][c2], ones8,
                                                           psacc[i], 0, 0, 0);
#pragma unroll
    for (int j = 0; j < 4; ++j) {
      const int d = 16 * j + l15;
      const int drow = d * 64;
      const int dsw = d & 7;
#pragma unroll
      for (int c2 = 0; c2 < 2; ++c2) {
        const bf16x8 vf =
            *(const bf16x8*)&Vs[drow + (((c2 * 4 + quad) ^ dsw) << 3)];
#pragma unroll
        for (int i = 0; i < 2; ++i)
          oacc[i][j] = __builtin_amdgcn_mfma_f32_16x16x32_bf16(pf[i][c2], vf,
                                                               oacc[i][j], 0, 0, 0);
      }
    }
    __builtin_amdgcn_s_setprio(0);
  }

  // divide by row-sum (lane-local) and store ATTN[token][h*64+d]
#pragma unroll
  for (int i = 0; i < 2; ++i) {
#pragma unroll
    for (int r = 0; r < 4; ++r) {
      const int m = q0 + wid * 32 + i * 16 + quad * 4 + r;
      const float invl = __builtin_amdgcn_rcpf(psacc[i][r]);
#pragma unroll
      for (int j = 0; j < 4; ++j)
        attn[((size_t)(b * S_LEN + m) * NH + h) * HEADD + j * 16 + l15] =
            (bf16)(oacc[i][j][r] * invl);
    }
  }
}

// ---------------- launcher ----------------
extern "C" void kernel_launch(void* const* d_in, const int* in_sizes, int n_in,
                              void* d_out, int out_size, void* d_ws,
                              size_t ws_size, hipStream_t stream) {
  const float* x = (const float*)d_in[0];
  const float* cosb = (const float*)d_in[1];
  const float* sinb = (const float*)d_in[2];
  const float* cnd = (const float*)d_in[3];
  const float* norm1_w = (const float*)d_in[4];
  const float* Wqkv = (const float*)d_in[5];
  const float* Wout = (const float*)d_in[6];
  const float* q_norm_w = (const float*)d_in[7];
  const float* k_norm_w = (const float*)d_in[8];
  const float* norm2_w = (const float*)d_in[9];
  const float* W1 = (const float*)d_in[10];
  const float* b1 = (const float*)d_in[11];
  const float* W2 = (const float*)d_in[12];
  const float* b2 = (const float*)d_in[13];
  const float* ada_W = (const float*)d_in[14];
  const float* ada_b = (const float*)d_in[15];
  float* out = (float*)d_out;

  char* p = (char*)d_ws;
  float* mod = (float*)p;   p += (size_t)4 * MODD * 4;        // (4,6144) f32
  bf16* WqkvT = (bf16*)p;   p += (size_t)3072 * 1024 * 2;
  bf16* WoutT = (bf16*)p;   p += (size_t)1024 * 1024 * 2;
  bf16* W1T = (bf16*)p;     p += (size_t)4096 * 1024 * 2;
  bf16* W2T = (bf16*)p;     p += (size_t)1024 * 4096 * 2;
  bf16* XN = (bf16*)p;      p += (size_t)NTOK * DIM * 2;      // ln1 out, reused ln2
  bf16* QKV = (bf16*)p;     p += (size_t)NTOK * 3 * DIM * 2;  // qkv (q/k roped)
  bf16* ATTN = (bf16*)p;    p += (size_t)NTOK * DIM * 2;
  bf16* Hbuf = (bf16*)p;    p += (size_t)NTOK * DFF * 2;
  // alias inside Hbuf (67 MB): consumed before gemm8 writes Hbuf
  bf16* VT = Hbuf;                                     // 16.8 MB

  init_mod_kernel<<<96, 256, 0, stream>>>(ada_b, mod);
  ada_gemm_kernel<<<dim3(24, 8), 256, 0, stream>>>(cnd, ada_W, mod);
  transpose_cast_kernel<<<dim3(96, 32), 256, 0, stream>>>(Wqkv, WqkvT, 1024, 3072);
  transpose_cast_kernel<<<dim3(32, 32), 256, 0, stream>>>(Wout, WoutT, 1024, 1024);
  transpose_cast_kernel<<<dim3(128, 32), 256, 0, stream>>>(W1, W1T, 1024, 4096);
  transpose_cast_kernel<<<dim3(32, 128), 256, 0, stream>>>(W2, W2T, 4096, 1024);
  ln_mod_kernel<<<NTOK, 256, 0, stream>>>(x, norm1_w, mod, 0, 1024, XN);
  gemm_bt<4, 128, 128><<<dim3(24, 64), 256, 0, stream>>>(
      XN, WqkvT, QKV, nullptr, nullptr, nullptr, nullptr, cosb, sinb,
      q_norm_w, k_norm_w, NTOK, 3072, 1024);
  vtrans_kernel<<<dim3(32, 64), 256, 0, stream>>>(QKV, VT);
  attn_kernel<<<dim3(16, 64), 256, 0, stream>>>(QKV, VT, ATTN);
  gemm_bt<1, 128, 128><<<dim3(8, 64), 256, 0, stream>>>(
      ATTN, WoutT, nullptr, out, nullptr, mod + 2 * 1024, x, nullptr, nullptr,
      nullptr, nullptr, NTOK, 1024, 1024);
  ln_mod_kernel<<<NTOK, 256, 0, stream>>>(out, norm2_w, mod, 3 * 1024, 4 * 1024, XN);
  gemm8<<<dim3(16, 32), 512, 0, stream>>>(XN, W1T, Hbuf, b1, NTOK, DFF, 1024);
  gemm_bt<3, 128, 128><<<dim3(8, 64), 256, 0, stream>>>(
      Hbuf, W2T, nullptr, out, b2, mod + 5 * 1024, out, nullptr, nullptr,
      nullptr, nullptr, NTOK, 1024, DFF);
  (void)in_sizes; (void)n_in; (void)out_size; (void)ws_size;
}

// Round 9
// 597.693 us; speedup vs baseline: 1.0359x; 1.0359x over previous
//
#include <hip/hip_runtime.h>
#include <hip/hip_bf16.h>
#include <math.h>

typedef __bf16 bf16;
typedef __bf16 bf16x8 __attribute__((ext_vector_type(8)));
typedef __bf16 bf16x4 __attribute__((ext_vector_type(4)));
typedef float f32x4 __attribute__((ext_vector_type(4)));
typedef short s16x4 __attribute__((ext_vector_type(4)));

#define S_LEN 2048
#define NTOK 8192          // B*S
#define DIM 1024
#define NH 16
#define HEADD 64
#define DFF 4096
#define MODD 6144          // 6*D
#define QSCALE 0.18033688011112042f   // 0.125 * log2(e), folded into q

// gelu(x) = 0.5x(1+tanh(u)) = x * sigmoid(2u); sigmoid via hw exp2+rcp.
__device__ __forceinline__ float gelu_fast(float x) {
  float u = 0.7978845608028654f * (x + 0.044715f * x * x * x);
  float e = __builtin_amdgcn_exp2f(-2.8853900817779268f * u);  // exp(-2u)
  return x * __builtin_amdgcn_rcpf(1.0f + e);
}

// 16B async global->LDS. LDS dest is wave-uniform base + lane*16 (HW rule);
// caller passes the per-wave base, per-lane global src.
__device__ __forceinline__ void gl_lds16(const bf16* g, bf16* l) {
  __builtin_amdgcn_global_load_lds(
      (const __attribute__((address_space(1))) unsigned int*)g,
      (__attribute__((address_space(3))) unsigned int*)l, 16, 0, 0);
}

// ---------------- mod = c @ ada_W + ada_b ----------------
__global__ __launch_bounds__(256) void init_mod_kernel(
    const float* __restrict__ ada_b, float* __restrict__ mod) {
  int i = blockIdx.x * 256 + threadIdx.x;   // 0..24575
  mod[i] = ada_b[i % MODD];
}

__global__ __launch_bounds__(256) void ada_gemm_kernel(
    const float* __restrict__ cnd, const float* __restrict__ W,
    float* __restrict__ mod) {
  int n = blockIdx.x * 256 + threadIdx.x;   // 0..6143
  int k0 = blockIdx.y * 128;
  float a0 = 0.f, a1 = 0.f, a2 = 0.f, a3 = 0.f;
  for (int k = k0; k < k0 + 128; ++k) {
    float w = W[(size_t)k * MODD + n];
    a0 = fmaf(cnd[k], w, a0);
    a1 = fmaf(cnd[1024 + k], w, a1);
    a2 = fmaf(cnd[2048 + k], w, a2);
    a3 = fmaf(cnd[3072 + k], w, a3);
  }
  atomicAdd(&mod[n], a0);
  atomicAdd(&mod[MODD + n], a1);
  atomicAdd(&mod[2 * MODD + n], a2);
  atomicAdd(&mod[3 * MODD + n], a3);
}

// ---------------- W (K,N) fp32 -> Wt (N,K) bf16 ----------------
__global__ __launch_bounds__(256) void transpose_cast_kernel(
    const float* __restrict__ W, bf16* __restrict__ Wt, int K, int N) {
  __shared__ float tile[32][33];
  int n0 = blockIdx.x * 32, k0 = blockIdx.y * 32;
  int r = threadIdx.x >> 3;
  int c4 = (threadIdx.x & 7) * 4;
  float4 v = *(const float4*)&W[(size_t)(k0 + r) * N + n0 + c4];
  tile[r][c4 + 0] = v.x; tile[r][c4 + 1] = v.y;
  tile[r][c4 + 2] = v.z; tile[r][c4 + 3] = v.w;
  __syncthreads();
  bf16x4 o;
  o[0] = (bf16)tile[c4 + 0][r];
  o[1] = (bf16)tile[c4 + 1][r];
  o[2] = (bf16)tile[c4 + 2][r];
  o[3] = (bf16)tile[c4 + 3][r];
  *(bf16x4*)&Wt[(size_t)(n0 + r) * K + k0 + c4] = o;
}

// ---------------- V part of qkv -> VT[b][h][d][s] ----------------
__global__ __launch_bounds__(256) void vtrans_kernel(
    const bf16* __restrict__ qkv, bf16* __restrict__ VT) {
  __shared__ __align__(16) bf16 t[64][72];
  const int bh = blockIdx.y;
  const int b = bh >> 4, h = bh & 15;
  const int s0 = blockIdx.x * 64;
  const int tid = threadIdx.x;
  {
    const int r = tid >> 2;
    const int c = (tid & 3) * 16;
    const bf16* src =
        qkv + (size_t)(b * S_LEN + s0 + r) * 3072 + 2048 + h * 64 + c;
    *(bf16x8*)&t[r][c] = *(const bf16x8*)src;
    *(bf16x8*)&t[r][c + 8] = *(const bf16x8*)(src + 8);
  }
  __syncthreads();
  {
    const int d = tid & 63;
    const int sc = (tid >> 6) * 16;
    bf16x8 o0, o1;
#pragma unroll
    for (int j = 0; j < 8; ++j) o0[j] = t[sc + j][d];
#pragma unroll
    for (int j = 0; j < 8; ++j) o1[j] = t[sc + 8 + j][d];
    bf16* dst = VT + (size_t)(bh * 64 + d) * S_LEN + s0 + sc;
    *(bf16x8*)dst = o0;
    *(bf16x8*)(dst + 8) = o1;
  }
}

// ---------------- LayerNorm + adaLN modulate -> bf16 ----------------
__global__ __launch_bounds__(256) void ln_mod_kernel(
    const float* __restrict__ x, const float* __restrict__ w,
    const float* __restrict__ mod, int sh_off, int sc_off,
    bf16* __restrict__ out) {
  __shared__ float red[8];
  const int row = blockIdx.x;
  const int b = row >> 11;          // row / 2048
  const int tid = threadIdx.x;
  const float4 v = ((const float4*)(x + (size_t)row * DIM))[tid];
  float s1 = v.x + v.y + v.z + v.w;
  float s2 = v.x * v.x + v.y * v.y + v.z * v.z + v.w * v.w;
  for (int off = 32; off > 0; off >>= 1) {
    s1 += __shfl_down(s1, off, 64);
    s2 += __shfl_down(s2, off, 64);
  }
  const int wid = tid >> 6;
  if ((tid & 63) == 0) { red[wid] = s1; red[4 + wid] = s2; }
  __syncthreads();
  s1 = red[0] + red[1] + red[2] + red[3];
  s2 = red[4] + red[5] + red[6] + red[7];
  const float mu = s1 * (1.0f / DIM);
  const float inv = rsqrtf(s2 * (1.0f / DIM) - mu * mu + 1e-5f);
  const int c = tid * 4;
  const float* mb = mod + (size_t)b * MODD;
  float xs[4] = {v.x, v.y, v.z, v.w};
  bf16x4 o;
#pragma unroll
  for (int j = 0; j < 4; ++j)
    o[j] = (bf16)(((xs[j] - mu) * inv) * w[c + j] * (1.0f + mb[sc_off + c + j]) +
                  mb[sh_off + c + j]);
  *(bf16x4*)(out + (size_t)row * DIM + c) = o;
}

// ---------------- bf16 MFMA GEMM, C = A(M,K) @ Bt(N,K)^T, fused epilogues ----
// 128x128 2-phase structure (controls: qkv / Wout / W2 this round).
// EPI 1: Cf = resid + g[b,n]*acc              (Wout proj -> d_out)
// EPI 3: Cf = resid + g[b,n]*(acc + bias)     (W2 -> d_out)
// EPI 4: qkv: q/k cols get fused RMSNorm+RoPE (q additionally scaled by
//        QSCALE so attn's softmax can use exp2 directly), v cols plain bf16
template <int EPI, int MT, int BN>
__global__ __launch_bounds__(256) void gemm_bt(
    const bf16* __restrict__ A, const bf16* __restrict__ Bt,
    bf16* __restrict__ Cb, float* __restrict__ Cf,
    const float* __restrict__ bias, const float* __restrict__ gmod,
    const float* __restrict__ resid, const float* __restrict__ cosb,
    const float* __restrict__ sinb, const float* __restrict__ qw,
    const float* __restrict__ kw, int M, int N, int K) {
  constexpr int IM = MT / 32;              // acc row-tiles per wave (4)
  constexpr int JN = BN / 32;              // acc col-tiles per wave (4)
  constexpr int AG = MT / 64;              // gload issues for A (2)
  constexpr int BG = BN / 64;              // gload issues for B (2)
  __shared__ __align__(16) bf16 As[3][MT * 32];   // 3 x 8 KB
  __shared__ __align__(16) bf16 Bs[3][BN * 32];
  const int tid = threadIdx.x;
  const int wid = tid >> 6;
  const int lane = tid & 63;
  const int l15 = lane & 15;
  const int quad = lane >> 4;

  // XCD-aware remap (gy assumed divisible by 8)
  const int gx = gridDim.x;
  const int flat = blockIdx.x + gx * blockIdx.y;
  const int xcd = flat & 7;
  const int idx = flat >> 3;
  const int ychunk = gridDim.y >> 3;
  const int bx = idx % gx;
  const int by = xcd * ychunk + idx / gx;
  const int m0 = by * MT;
  const int n0 = bx * BN;

  const int wm = (wid & 1) * (MT / 2);
  const int wn = (wid >> 1) * (BN / 2);

  const int srow = wid * 16 + (lane >> 2);
  const int scol = (lane & 3) * 8;
  const bf16* Ap = A + (size_t)(m0 + srow) * K + scol;
  const bf16* Bp = Bt + (size_t)(n0 + srow) * K + scol;

  auto stage = [&](int buf, int kt) {
#pragma unroll
    for (int g = 0; g < AG; ++g)
      gl_lds16(Ap + (size_t)g * 64 * K + kt, As[buf] + g * 2048 + wid * 512);
#pragma unroll
    for (int g = 0; g < BG; ++g)
      gl_lds16(Bp + (size_t)g * 64 * K + kt, Bs[buf] + g * 2048 + wid * 512);
  };

  // prologue: tiles 0 and 1 in flight
  stage(0, 0);
  stage(1, 32);

  f32x4 acc[IM][JN] = {};
  const int NT = K >> 5;
  int cur = 0, stg = 2;

  for (int t = 0; t < NT; ++t) {
    if (t + 2 < NT) {
      stage(stg, (t + 2) << 5);
      asm volatile("s_waitcnt vmcnt(8)" ::: "memory");   // tile t landed
    } else if (t + 1 < NT) {
      asm volatile("s_waitcnt vmcnt(4)" ::: "memory");
    } else {
      asm volatile("s_waitcnt vmcnt(0)" ::: "memory");
    }
    __builtin_amdgcn_s_barrier();   // all waves' tile-t DMA visible

    bf16x8 af[IM], bfr[JN];
#pragma unroll
    for (int i = 0; i < IM; ++i)
      af[i] = *(const bf16x8*)&As[cur][(wm + i * 16 + l15) * 32 + quad * 8];
#pragma unroll
    for (int j = 0; j < JN; ++j)
      bfr[j] = *(const bf16x8*)&Bs[cur][(wn + j * 16 + l15) * 32 + quad * 8];
    __builtin_amdgcn_s_setprio(1);
#pragma unroll
    for (int i = 0; i < IM; ++i)
#pragma unroll
      for (int j = 0; j < JN; ++j)
        acc[i][j] = __builtin_amdgcn_mfma_f32_16x16x32_bf16(af[i], bfr[j],
                                                            acc[i][j], 0, 0, 0);
    __builtin_amdgcn_s_setprio(0);
    __builtin_amdgcn_s_barrier();   // gates next step's overwrite of buf cur-1
    cur = (cur == 2) ? 0 : cur + 1;
    stg = (stg == 2) ? 0 : stg + 1;
  }

  if (EPI == 4 && n0 < 2048) {
    // q/k columns: fused RMSNorm (over the 64-dim head) + RoPE.
    const bool isq = (n0 + wn) < 1024;
    const float* nw = isq ? qw : kw;
    const float osc = isq ? QSCALE : 1.0f;   // fold softmax scale into q
    float wv[4];
#pragma unroll
    for (int j = 0; j < 4; ++j) wv[j] = nw[j * 16 + l15];
#pragma unroll
    for (int i = 0; i < IM; ++i) {
#pragma unroll
      for (int r = 0; r < 4; ++r) {
        const int m = m0 + wm + i * 16 + quad * 4 + r;
        const int s = m & (S_LEN - 1);
        float v[4];
        float ss = 0.f;
#pragma unroll
        for (int j = 0; j < 4; ++j) { v[j] = acc[i][j][r]; ss += v[j] * v[j]; }
        ss += __shfl_xor(ss, 1, 64);
        ss += __shfl_xor(ss, 2, 64);
        ss += __shfl_xor(ss, 4, 64);
        ss += __shfl_xor(ss, 8, 64);
        const float inv = rsqrtf(ss * (1.0f / HEADD) + 1e-6f);
        float xn[4];
#pragma unroll
        for (int j = 0; j < 4; ++j) xn[j] = v[j] * inv * wv[j];
#pragma unroll
        for (int j = 0; j < 4; ++j) {
          const int d = j * 16 + l15;
          const float rot = (j < 2) ? -xn[j + 2] : xn[j - 2];
          const float o =
              (xn[j] * cosb[s * HEADD + d] + rot * sinb[s * HEADD + d]) * osc;
          Cb[(size_t)m * N + n0 + wn + d] = (bf16)o;
        }
      }
    }
    return;
  }

#pragma unroll
  for (int i = 0; i < IM; ++i) {
#pragma unroll
    for (int r = 0; r < 4; ++r) {
      const int m = m0 + wm + i * 16 + quad * 4 + r;   // C row = quad*4+reg
#pragma unroll
      for (int j = 0; j < JN; ++j) {
        const int n = n0 + wn + j * 16 + l15;          // C col = lane&15
        float v = acc[i][j][r];
        if (EPI == 0 || EPI == 4) {
          Cb[(size_t)m * N + n] = (bf16)v;
        } else if (EPI == 1) {
          const int b = m >> 11;
          Cf[(size_t)m * N + n] =
              resid[(size_t)m * N + n] + gmod[(size_t)b * MODD + n] * v;
        } else if (EPI == 2) {
          v += bias[n];
          Cb[(size_t)m * N + n] = (bf16)gelu_fast(v);
        } else {
          v += bias[n];
          const int b = m >> 11;
          Cf[(size_t)m * N + n] =
              resid[(size_t)m * N + n] + gmod[(size_t)b * MODD + n] * v;
        }
      }
    }
  }
}

// ---------------- 8-phase 256^2 GEMM (T3+T4) + T2 swizzle, W1 only ----------
// r8's 8-phase was invalidated by 16-way LDS bank conflicts (BANK_CONFLICT
// 1.89e7): [row][64] bf16 rows are 128 B, so a fixed 16B column across rows
// puts 16 lanes on one bank (G4/m201). Fix per rule #21 (both-sides-or-
// neither with global_load_lds): LDS dest stays LINEAR; the per-lane GLOBAL
// source column is pre-swizzled  slot ^= (row&7)  so data lands XOR-swizzled;
// every ds_read applies the same XOR  chunk = (kk*4+quad) ^ (row&7).
// Lanes l15=0..7 then hit 8 distinct 16B slots spanning all 32 banks; l15+8
// aliases 2-way = free (m136). Schedule identical to r8: 4 sub-phases/tile,
// counted vmcnt(2) once per tile (never 0 in the loop), 2x64 KB dbuf.
// EPI 2 only: Cb = bf16(gelu(acc + bias)).
__global__ __launch_bounds__(512) void gemm8(
    const bf16* __restrict__ A, const bf16* __restrict__ Bt,
    bf16* __restrict__ Cb, const float* __restrict__ bias, int M, int N,
    int K) {
  __shared__ __align__(16) bf16 As[2][16384];   // 2 x 32 KB: [row<256][k<64]
  __shared__ __align__(16) bf16 Bs[2][16384];
  const int tid = threadIdx.x;
  const int wid = tid >> 6;                // 0..7
  const int lane = tid & 63;
  const int l15 = lane & 15;
  const int quad = lane >> 4;
  const int wr = wid & 1;                  // M half (128 rows)
  const int wc = wid >> 1;                 // N quarter (64 cols)
  const int swz = l15 & 7;                 // read-side row XOR

  // XCD-aware remap (gy divisible by 8; W1: gx=16, gy=32)
  const int gx = gridDim.x;
  const int flat = blockIdx.x + gx * blockIdx.y;
  const int xcd = flat & 7;
  const int idx = flat >> 3;
  const int ychunk = gridDim.y >> 3;
  const int bx = idx % gx;
  const int by = xcd * ychunk + idx / gx;
  const int m0 = by * 256;
  const int n0 = bx * 256;

  // staging: thread covers LDS row q*64 + (tid>>3), slot tid&7 (linear dest).
  // Pre-swizzled SOURCE: slot s of row r receives global chunk s ^ (r&7).
  const int rrow = tid >> 3;
  const int rcol = ((tid & 7) ^ (rrow & 7)) * 8;   // inverse-swz global col
  const bf16* Ap = A + (size_t)(m0 + rrow) * K + rcol;
  const bf16* Bp = Bt + (size_t)(n0 + rrow) * K + rcol;

  auto stage2 = [&](int buf, int kt, int q0) {
#pragma unroll
    for (int q = q0; q < q0 + 2; ++q) {
      if (q < 4)
        gl_lds16(Ap + (size_t)q * 64 * K + kt, As[buf] + q * 4096 + wid * 512);
      else
        gl_lds16(Bp + (size_t)(q - 4) * 64 * K + kt,
                 Bs[buf] + (q - 4) * 4096 + wid * 512);
    }
  };

  // prologue: stage tile 0 fully into buf 0
  stage2(0, 0, 0); stage2(0, 0, 2); stage2(0, 0, 4); stage2(0, 0, 6);

  f32x4 acc[8][4] = {};
  const int NT = K >> 6;
  int cur = 0;

  for (int t = 0; t < NT; ++t) {
    const int ktn = (t + 1) << 6;
    int qp = 0;
#pragma unroll
    for (int kk = 0; kk < 2; ++kk) {
      bf16x8 bfr[4];
#pragma unroll
      for (int ih = 0; ih < 2; ++ih) {
        // stage 2 loads of tile t+1 into the other buffer
        if (t + 1 < NT) stage2(cur ^ 1, ktn, qp * 2);
        if (qp == 0) {
          if (t + 1 < NT)
            asm volatile("s_waitcnt vmcnt(2)" ::: "memory");  // tile t landed
          else
            asm volatile("s_waitcnt vmcnt(0)" ::: "memory");
          __builtin_amdgcn_s_barrier();   // all waves' tile-t DMA visible
        }
        if (ih == 0) {   // B frags for this kk (swizzled read), reused by ih
#pragma unroll
          for (int j = 0; j < 4; ++j)
            bfr[j] = *(const bf16x8*)&Bs[cur][(wc * 64 + j * 16 + l15) * 64 +
                                              (((kk * 4 + quad) ^ swz) << 3)];
        }
        bf16x8 af[4];
#pragma unroll
        for (int ii = 0; ii < 4; ++ii)
          af[ii] = *(const bf16x8*)&As[cur][(wr * 128 + (ih * 4 + ii) * 16 +
                                             l15) * 64 +
                                            (((kk * 4 + quad) ^ swz) << 3)];
        __builtin_amdgcn_s_setprio(1);
#pragma unroll
        for (int ii = 0; ii < 4; ++ii)
#pragma unroll
          for (int j = 0; j < 4; ++j)
            acc[ih * 4 + ii][j] = __builtin_amdgcn_mfma_f32_16x16x32_bf16(
                af[ii], bfr[j], acc[ih * 4 + ii][j], 0, 0, 0);
        __builtin_amdgcn_s_setprio(0);
        __builtin_amdgcn_s_barrier();
        ++qp;
      }
    }
    cur ^= 1;
  }

  // EPI 2: Cb = bf16(gelu(acc + bias))
#pragma unroll
  for (int i = 0; i < 8; ++i) {
#pragma unroll
    for (int r = 0; r < 4; ++r) {
      const int m = m0 + wr * 128 + i * 16 + quad * 4 + r;
#pragma unroll
      for (int j = 0; j < 4; ++j) {
        const int n = n0 + wc * 64 + j * 16 + l15;
        float v = acc[i][j][r] + bias[n];
        Cb[(size_t)m * N + n] = (bf16)gelu_fast(v);
      }
    }
  }
}

// ---------------- flash attention: single-pass, full-rate PV ----------------
// q is pre-scaled by QSCALE in the qkv epilogue, so the softmax numerator is
// exp2(sc) directly (no fmaf, no shift -- any fixed shift cancels in the
// final division). Single-pass over 32 KV tiles, QBLK=128 -> 1024 blocks =
// 4/CU. K rows stored in LDS permuted by sig(p) so each lane's S^T C-frags
// hold exactly keys quad*8+j: P packs into 16x16x32 A-frags in registers,
// PV runs at full rate. psum via ones-frag MFMA; division is lane-local.
// XCD remap: 16 q-blocks of one bh on one XCD.
__global__ __launch_bounds__(256) void attn_kernel(
    const bf16* __restrict__ qkv, const bf16* __restrict__ VT,
    bf16* __restrict__ attn) {
  __shared__ __align__(16) bf16 Ks[4096];   // [sig(key)][feat], chunk^=(row&7)
  __shared__ __align__(16) bf16 Vs[4096];   // [feat d][key], chunk^=(d&7)
  const int flat = blockIdx.x + 16 * blockIdx.y;
  const int xcd = flat & 7;
  const int idx = flat >> 3;             // 0..127
  const int bh = xcd * 8 + (idx >> 4);   // 0..63
  const int qblk = idx & 15;
  const int b = bh >> 4;
  const int h = bh & 15;
  const int q0 = qblk * 128;
  const int tid = threadIdx.x;
  const int wid = tid >> 6;
  const int lane = tid & 63;
  const int l15 = lane & 15;
  const int quad = lane >> 4;

  // Q fragments (B-operand: n=qrow=l15, k=feat quad*8+j)
  bf16x8 aq[2][2];
#pragma unroll
  for (int i = 0; i < 2; ++i) {
    const int qrow = q0 + wid * 32 + i * 16 + l15;
    const size_t qbase = (size_t)(b * S_LEN + qrow) * (3 * DIM) + h * HEADD;
    aq[i][0] = *(const bf16x8*)(qkv + qbase + quad * 8);
    aq[i][1] = *(const bf16x8*)(qkv + qbase + 32 + quad * 8);
  }

  // staging: lane stages global key/feat row `lane`; K lands at permuted row
  const int ksrow = (lane & 32) | ((lane & 4) << 2) | ((lane & 24) >> 1) | (lane & 3);
  const int ksw = ksrow & 7;
  const int vsw = lane & 7;
  const bf16* krow =
      qkv + (size_t)(b * S_LEN + lane) * 3072 + DIM + h * HEADD;
  const bf16* vrow = VT + (size_t)(bh * 64 + lane) * S_LEN;

  bf16x8 kreg[2], vreg[2];
#pragma unroll
  for (int rr = 0; rr < 2; ++rr) {
    const int ck = wid + 4 * rr;
    kreg[rr] = *(const bf16x8*)(krow + ck * 8);
    vreg[rr] = *(const bf16x8*)(vrow + ck * 8);
  }

  const bf16 one = (bf16)1.0f;
  const bf16x8 ones8 = {one, one, one, one, one, one, one, one};
  f32x4 oacc[2][4] = {};
  f32x4 psacc[2] = {};    // rowsum C-frag: lane holds qrow quad*4+r

  for (int t = 0; t < 32; ++t) {
    __syncthreads();   // previous tile's LDS reads done
#pragma unroll
    for (int rr = 0; rr < 2; ++rr) {
      const int ck = wid + 4 * rr;
      *(bf16x8*)&Ks[ksrow * 64 + ((ck ^ ksw) << 3)] = kreg[rr];
      *(bf16x8*)&Vs[lane * 64 + ((ck ^ vsw) << 3)] = vreg[rr];
    }
    __syncthreads();
    if (t < 31) {     // prefetch next tile while computing this one
      krow += 64 * 3072;
      vrow += 64;
#pragma unroll
      for (int rr = 0; rr < 2; ++rr) {
        const int ck = wid + 4 * rr;
        kreg[rr] = *(const bf16x8*)(krow + ck * 8);
        vreg[rr] = *(const bf16x8*)(vrow + ck * 8);
      }
    }

    // S^T = K·Q^T  (A = permuted K rows, B = Q^T): D[sig(key)][qrow]
    f32x4 sc[2][4] = {};
    __builtin_amdgcn_s_setprio(1);
#pragma unroll
    for (int hh = 0; hh < 2; ++hh) {
#pragma unroll
      for (int cc = 0; cc < 4; ++cc) {
        const int row = cc * 16 + l15;
        const bf16x8 kf =
            *(const bf16x8*)&Ks[row * 64 + (((quad + 4 * hh) ^ (l15 & 7)) << 3)];
#pragma unroll
        for (int i = 0; i < 2; ++i)
          sc[i][cc] = __builtin_amdgcn_mfma_f32_16x16x32_bf16(kf, aq[i][hh],
                                                              sc[i][cc], 0, 0, 0);
      }
    }
    __builtin_amdgcn_s_setprio(0);

    // softmax numerator: p = exp2(sc) (scale folded into q; shift cancels
    // in the division). Pack P into 16x16x32 A-frags.
    // sc slot (cc=2*c2+(j>>2), r=j&3) holds physical key c2*32+quad*8+j.
    bf16x8 pf[2][2];
#pragma unroll
    for (int i = 0; i < 2; ++i)
#pragma unroll
      for (int c2 = 0; c2 < 2; ++c2) {
        bf16x8 pb;
#pragma unroll
        for (int j = 0; j < 8; ++j) {
          const float p =
              __builtin_amdgcn_exp2f(sc[i][2 * c2 + (j >> 2)][j & 3]);
          pb[j] = (bf16)p;
        }
        pf[i][c2] = pb;
      }

    // psum row-sums via ones B-frag, then O += P·V at full 16x16x32 rate
    __builtin_amdgcn_s_setprio(1);
#pragma unroll
    for (int i = 0; i < 2; ++i)
#pragma unroll
      for (int c2 = 0; c2 < 2; ++c2)
        psacc[i] = __builtin_amdgcn_mfma_f32_16x16x32_bf16(pf[i][c2], ones8,
                                                           psacc[i], 0, 0, 0);
#pragma unroll
    for (int j = 0; j < 4; ++j) {
      const int d = 16 * j + l15;
      const int drow = d * 64;
      const int dsw = d & 7;
#pragma unroll
      for (int c2 = 0; c2 < 2; ++c2) {
        const bf16x8 vf =
            *(const bf16x8*)&Vs[drow + (((c2 * 4 + quad) ^ dsw) << 3)];
#pragma unroll
        for (int i = 0; i < 2; ++i)
          oacc[i][j] = __builtin_amdgcn_mfma_f32_16x16x32_bf16(pf[i][c2], vf,
                                                               oacc[i][j], 0, 0, 0);
      }
    }
    __builtin_amdgcn_s_setprio(0);
  }

  // divide by row-sum (lane-local) and store ATTN[token][h*64+d]
#pragma unroll
  for (int i = 0; i < 2; ++i) {
#pragma unroll
    for (int r = 0; r < 4; ++r) {
      const int m = q0 + wid * 32 + i * 16 + quad * 4 + r;
      const float invl = __builtin_amdgcn_rcpf(psacc[i][r]);
#pragma unroll
      for (int j = 0; j < 4; ++j)
        attn[((size_t)(b * S_LEN + m) * NH + h) * HEADD + j * 16 + l15] =
            (bf16)(oacc[i][j][r] * invl);
    }
  }
}

// ---------------- launcher ----------------
extern "C" void kernel_launch(void* const* d_in, const int* in_sizes, int n_in,
                              void* d_out, int out_size, void* d_ws,
                              size_t ws_size, hipStream_t stream) {
  const float* x = (const float*)d_in[0];
  const float* cosb = (const float*)d_in[1];
  const float* sinb = (const float*)d_in[2];
  const float* cnd = (const float*)d_in[3];
  const float* norm1_w = (const float*)d_in[4];
  const float* Wqkv = (const float*)d_in[5];
  const float* Wout = (const float*)d_in[6];
  const float* q_norm_w = (const float*)d_in[7];
  const float* k_norm_w = (const float*)d_in[8];
  const float* norm2_w = (const float*)d_in[9];
  const float* W1 = (const float*)d_in[10];
  const float* b1 = (const float*)d_in[11];
  const float* W2 = (const float*)d_in[12];
  const float* b2 = (const float*)d_in[13];
  const float* ada_W = (const float*)d_in[14];
  const float* ada_b = (const float*)d_in[15];
  float* out = (float*)d_out;

  char* p = (char*)d_ws;
  float* mod = (float*)p;   p += (size_t)4 * MODD * 4;        // (4,6144) f32
  bf16* WqkvT = (bf16*)p;   p += (size_t)3072 * 1024 * 2;
  bf16* WoutT = (bf16*)p;   p += (size_t)1024 * 1024 * 2;
  bf16* W1T = (bf16*)p;     p += (size_t)4096 * 1024 * 2;
  bf16* W2T = (bf16*)p;     p += (size_t)1024 * 4096 * 2;
  bf16* XN = (bf16*)p;      p += (size_t)NTOK * DIM * 2;      // ln1 out, reused ln2
  bf16* QKV = (bf16*)p;     p += (size_t)NTOK * 3 * DIM * 2;  // qkv (q/k roped)
  bf16* ATTN = (bf16*)p;    p += (size_t)NTOK * DIM * 2;
  bf16* Hbuf = (bf16*)p;    p += (size_t)NTOK * DFF * 2;
  // alias inside Hbuf (67 MB): consumed before gemm8 writes Hbuf
  bf16* VT = Hbuf;                                     // 16.8 MB

  init_mod_kernel<<<96, 256, 0, stream>>>(ada_b, mod);
  ada_gemm_kernel<<<dim3(24, 8), 256, 0, stream>>>(cnd, ada_W, mod);
  transpose_cast_kernel<<<dim3(96, 32), 256, 0, stream>>>(Wqkv, WqkvT, 1024, 3072);
  transpose_cast_kernel<<<dim3(32, 32), 256, 0, stream>>>(Wout, WoutT, 1024, 1024);
  transpose_cast_kernel<<<dim3(128, 32), 256, 0, stream>>>(W1, W1T, 1024, 4096);
  transpose_cast_kernel<<<dim3(32, 128), 256, 0, stream>>>(W2, W2T, 4096, 1024);
  ln_mod_kernel<<<NTOK, 256, 0, stream>>>(x, norm1_w, mod, 0, 1024, XN);
  gemm_bt<4, 128, 128><<<dim3(24, 64), 256, 0, stream>>>(
      XN, WqkvT, QKV, nullptr, nullptr, nullptr, nullptr, cosb, sinb,
      q_norm_w, k_norm_w, NTOK, 3072, 1024);
  vtrans_kernel<<<dim3(32, 64), 256, 0, stream>>>(QKV, VT);
  attn_kernel<<<dim3(16, 64), 256, 0, stream>>>(QKV, VT, ATTN);
  gemm_bt<1, 128, 128><<<dim3(8, 64), 256, 0, stream>>>(
      ATTN, WoutT, nullptr, out, nullptr, mod + 2 * 1024, x, nullptr, nullptr,
      nullptr, nullptr, NTOK, 1024, 1024);
  ln_mod_kernel<<<NTOK, 256, 0, stream>>>(out, norm2_w, mod, 3 * 1024, 4 * 1024, XN);
  gemm8<<<dim3(16, 32), 512, 0, stream>>>(XN, W1T, Hbuf, b1, NTOK, DFF, 1024);
  gemm_bt<3, 128, 128><<<dim3(8, 64), 256, 0, stream>>>(
      Hbuf, W2T, nullptr, out, b2, mod + 5 * 1024, out, nullptr, nullptr,
      nullptr, nullptr, NTOK, 1024, DFF);
  (void)in_sizes; (void)n_in; (void)out_size; (void)ws_size;
}